// Round 11
// baseline (181.915 us; speedup 1.0000x reference)
//
#include <hip/hip_runtime.h>
#include <hip/hip_bf16.h>

typedef unsigned short u16;
typedef short bf16x8 __attribute__((ext_vector_type(8)));
typedef float f32x4 __attribute__((ext_vector_type(4)));
typedef int   i32x4 __attribute__((ext_vector_type(4)));

#define NB 8
#define NT 1024
#define ND 512
#define KSEL 307
#define PSTR 152   // attn P LDS row stride (elems)
#define TSTR 136   // gemm_wh transpose LDS row stride (elems)
#define AS2 520    // gemm2out A-panel stride (elems)
#define BS2 36     // gemm2out B-slice stride (elems)

__device__ __forceinline__ float bf2f(u16 u){
  union { unsigned int i; float f; } c; c.i = ((unsigned int)u) << 16; return c.f;
}
__device__ __forceinline__ u16 f2bf(float f){
  __hip_bfloat16 h = __float2bfloat16(f);
  u16 u; __builtin_memcpy(&u, &h, 2); return u;
}

// ---------- WcatT[c][d] = W[h=c>>6][d][f=c&63];  W2T[n][k] = W2[k][n]  (bf16)
__global__ void k_convert_w(const float* __restrict__ W, const float* __restrict__ W2,
                            u16* __restrict__ WcatT, u16* __restrict__ W2T){
  int idx = blockIdx.x * 256 + threadIdx.x;          // 0 .. 524287
  if (idx < 262144){
    int c = idx >> 9, d = idx & 511;
    int src = ((c >> 6) << 15) | (d << 6) | (c & 63);
    WcatT[idx] = f2bf(W[src]);
  } else {
    int i = idx - 262144;
    int n = i >> 9, k = i & 511;
    W2T[i] = f2bf(W2[(k << 9) | n]);
  }
}

// ---------- exact top-k selection by ranking; 4 threads per t, 64 t per block
__global__ void k_select(const float* __restrict__ mags, int* __restrict__ sel){
  __shared__ float sm[NT];
  int b = blockIdx.x;
  int tid = threadIdx.x;
  for (int i = tid; i < NT; i += 256) sm[i] = mags[b * NT + i];
  __syncthreads();
  int tl = tid >> 2, tq = tid & 3;
  int t = blockIdx.y * 64 + tl;
  float m = sm[t];
  int cnt = 0;
  int s0 = tq * 256;
  for (int s = s0; s < s0 + 256; s++){
    float v = sm[s];
    cnt += (v > m) || (v == m && s < t);
  }
  cnt += __shfl_xor(cnt, 1, 64);
  cnt += __shfl_xor(cnt, 2, 64);
  if (tq == 0) sel[b * NT + t] = (cnt < KSEL) ? 1 : 0;
}

// ---------- MFMA bf16 GEMM: Wh = bf16(x) @ Wcat ; tile 128(t) x 64(f = one head)
//   epilogue fuses: row mags (by==0), es/ed edge dots, transposed bf16 WhT write
__launch_bounds__(256, 3)
__global__ void k_gemm_wh(const float* __restrict__ x, const u16* __restrict__ Bt,
                          const float* __restrict__ a_src, const float* __restrict__ a_dst,
                          u16* __restrict__ WhT, float* __restrict__ es, float* __restrict__ ed,
                          float* __restrict__ mags){
  __shared__ u16 smem[8704];         // 17408 B; As(5120)+Bs(2560) alias Tr(64*TSTR)
  u16* As = smem;                    // 128 x 40
  u16* Bs = smem + 5120;             // 64 x 40
  int m0 = blockIdx.x * 128;         // t-block
  int h  = blockIdx.y;               // head (n0 = h*64)
  int tid = threadIdx.x;
  int wv = tid >> 6, lane = tid & 63;
  int quad = lane >> 4, lr = lane & 15;
  f32x4 acc[2][4] = {};
  float sq[2] = {0.f, 0.f};
  for (int kt = 0; kt < 512; kt += 32){
    __syncthreads();
#pragma unroll
    for (int i = 0; i < 2; i++){
      int e = tid * 8 + i * 2048;
      int r = e >> 5, c = e & 31;
      const float* xa = &x[(m0 + r) * 512 + kt + c];
      f32x4 u0 = *(const f32x4*)xa;
      f32x4 u1 = *(const f32x4*)(xa + 4);
      u16 pk[8];
#pragma unroll
      for (int q = 0; q < 4; q++){
        sq[i] += u0[q]*u0[q] + u1[q]*u1[q];
        pk[q] = f2bf(u0[q]); pk[4+q] = f2bf(u1[q]);
      }
      *(bf16x8*)&As[r*40 + c] = *(const bf16x8*)pk;
    }
    {
      int e = tid * 8;               // 0..2047 exactly covers 64x32
      int r = e >> 5, c = e & 31;
      *(bf16x8*)&Bs[r*40 + c] = *(const bf16x8*)&Bt[(h * 64 + r) * 512 + kt + c];
    }
    __syncthreads();
    bf16x8 af[2], bfr[4];
#pragma unroll
    for (int i = 0; i < 2; i++) af[i] = *(const bf16x8*)&As[(wv*32 + i*16 + lr)*40 + quad*8];
#pragma unroll
    for (int i = 0; i < 4; i++) bfr[i] = *(const bf16x8*)&Bs[(i*16 + lr)*40 + quad*8];
#pragma unroll
    for (int mi = 0; mi < 2; mi++)
#pragma unroll
      for (int ni = 0; ni < 4; ni++)
        acc[mi][ni] = __builtin_amdgcn_mfma_f32_16x16x32_bf16(af[mi], bfr[ni], acc[mi][ni], 0, 0, 0);
  }
  // ---- epilogue 0: row L2 norms (4 lanes per row)
  if (blockIdx.y == 0){
#pragma unroll
    for (int i = 0; i < 2; i++){
      float s = sq[i];
      s += __shfl_xor(s, 1, 64);
      s += __shfl_xor(s, 2, 64);
      if ((tid & 3) == 0) mags[m0 + i*64 + (tid >> 2)] = sqrtf(s);
    }
  }
  // ---- epilogue 1: edge dot products (wave owns rows wv*32..+32, full head width)
  float asv[4], adv[4];
#pragma unroll
  for (int ni = 0; ni < 4; ni++){
    asv[ni] = a_src[h*64 + ni*16 + lr];
    adv[ni] = a_dst[h*64 + ni*16 + lr];
  }
#pragma unroll
  for (int mi = 0; mi < 2; mi++)
#pragma unroll
    for (int r = 0; r < 4; r++){
      float pes = 0.f, ped = 0.f;
#pragma unroll
      for (int ni = 0; ni < 4; ni++){
        pes += acc[mi][ni][r] * asv[ni];
        ped += acc[mi][ni][r] * adv[ni];
      }
#pragma unroll
      for (int mofs = 1; mofs < 16; mofs <<= 1){
        pes += __shfl_xor(pes, mofs, 64);
        ped += __shfl_xor(ped, mofs, 64);
      }
      if (lr == 0){
        int rowg = m0 + wv*32 + mi*16 + quad*4 + r;
        int bb_ = rowg >> 10, tt = rowg & 1023;
        es[(bb_ * 8 + h) * NT + tt] = pes;
        ed[(bb_ * 8 + h) * NT + tt] = ped;
      }
    }
  // ---- epilogue 2: bf16 transpose via LDS -> WhT[(b*512 + h*64 + f)][t]
  __syncthreads();
  u16* Tr = smem;   // [f][t], stride TSTR
#pragma unroll
  for (int mi = 0; mi < 2; mi++)
#pragma unroll
    for (int ni = 0; ni < 4; ni++){
      int fl = ni*16 + lr;
      int tl = wv*32 + mi*16 + quad*4;
#pragma unroll
      for (int r = 0; r < 4; r++) Tr[fl*TSTR + tl + r] = f2bf(acc[mi][ni][r]);
    }
  __syncthreads();
  int f = tid >> 2, seg = tid & 3;
  int b_ = m0 >> 10;
  u16* dst = &WhT[(b_ * 512 + h * 64 + f) * NT + (m0 & 1023) + seg*32];
  const u16* srcp = &Tr[f*TSTR + seg*32];
#pragma unroll
  for (int k8 = 0; k8 < 4; k8++)
    *(bf16x8*)(dst + k8*8) = *(const bf16x8*)(srcp + k8*8);
}

// ---------- banded masked attention via MFMA + elu + signed-sqrt -> t2b (bf16)
//            + fused column sum-of-squares (atomicAdd into cn)
__launch_bounds__(256)
__global__ void k_attn(const u16* __restrict__ WhT, const float* __restrict__ es,
                       const float* __restrict__ ed, const int* __restrict__ sel,
                       u16* __restrict__ t2b, float* __restrict__ cn){
  __shared__ u16 P[64 * PSTR];
  __shared__ float edw[144];
  __shared__ int   selw[144];
  __shared__ float esw[64];
  __shared__ float swv[64];
  int bh = blockIdx.x;               // b*8+h
  int b = bh >> 3;
  int t0 = blockIdx.y * 64;
  int tid = threadIdx.x;
  int wv = tid >> 6, lane = tid & 63;
  int quad = lane >> 4, lr = lane & 15;
  int s_base = t0 - 40;
  for (int i = tid; i < 144; i += 256){
    int s = s_base + i;
    bool ok = (s >= 0 && s < NT);
    edw[i]  = ok ? ed[bh * NT + s] : 0.f;
    selw[i] = ok ? sel[b * NT + s] : 0;
  }
  if (tid < 64) esw[tid] = es[bh * NT + t0 + tid];
  {
    i32x4 z = {};
    for (int i = lane; i < 304; i += 64){
      int r16 = i / 19, c16 = i - r16 * 19;
      *(i32x4*)&P[(16*wv + r16) * PSTR + c16 * 8] = z;
    }
  }
  __syncthreads();
  {
    int tl = 16*wv + (lane >> 2);
    int q = lane & 3;
    float e_t = esw[tl];
    int sel_t = selw[tl + 40];
    float part = 0.f;
    for (int j = q; j <= 80; j += 4){
      int sw = tl + j;
      int s = s_base + sw;
      float w = 0.f;
      if (s >= 0 && s < NT && (sel_t | selw[sw])){
        float v = e_t + edw[sw];
        v = v > 0.f ? v : 0.2f * v;
        v = fminf(v, 60.f);
        w = bf2f(f2bf(__expf(v)));
      }
      part += w;
      if (w != 0.f) P[tl * PSTR + sw] = f2bf(w);
    }
    part += __shfl_xor(part, 1, 64);
    part += __shfl_xor(part, 2, 64);
    if (q == 0) swv[tl] = part;
  }
  f32x4 acc[4] = {};
  const u16* vbase = WhT + (bh * 64) * NT;
#pragma unroll
  for (int ks = 0; ks < 96; ks += 32){
    bf16x8 afr = *(const bf16x8*)&P[(16*wv + lr) * PSTR + 16*wv + ks + quad*8];
    int tb = s_base + 16*wv + ks + quad*8;
    bool ok = (tb >= 0) && (tb < NT);
    bf16x8 zf = {};
#pragma unroll
    for (int jn = 0; jn < 4; jn++){
      bf16x8 bfr = ok ? *(const bf16x8*)&vbase[(16*jn + lr) * NT + tb] : zf;
      acc[jn] = __builtin_amdgcn_mfma_f32_16x16x32_bf16(afr, bfr, acc[jn], 0, 0, 0);
    }
  }
#pragma unroll
  for (int jn = 0; jn < 4; jn++){
    float ssum = 0.f;
#pragma unroll
    for (int r = 0; r < 4; r++){
      int t_loc = 16*wv + quad*4 + r;
      float sw_ = swv[t_loc];
      float hp = acc[jn][r] / (sw_ > 0.f ? sw_ : 1.f);
      hp = hp > 0.f ? hp : (__expf(hp) - 1.f);
      float o = hp >= 0.f ? sqrtf(hp) : -sqrtf(-hp);
      ssum += o * o;
      t2b[(b * NT + t0 + t_loc) * ND + (bh & 7) * 64 + 16*jn + lr] = f2bf(o);
    }
    ssum += __shfl_xor(ssum, 16, 64);
    ssum += __shfl_xor(ssum, 32, 64);
    if (quad == 0) atomicAdd(&cn[b * ND + (bh & 7) * 64 + 16*jn + lr], ssum);
  }
}

// ---------- GEMM2+LN+transpose fused: block = 32 t-rows x full 512 cols
//   y = (t2b*scl) @ W2 + x + b2 computed in registers; LN stats block-local;
//   apply + transpose via LDS; writes out[b,d,t] directly. No Y buffer.
__launch_bounds__(256, 2)
__global__ void k_gemm2out(const u16* __restrict__ A, const u16* __restrict__ Bt,
                           const float* __restrict__ xres, const float* __restrict__ b2,
                           const float* __restrict__ cn, const float* __restrict__ g,
                           const float* __restrict__ bb, float* __restrict__ out){
  __shared__ i32x4 smemQ[4384];          // 70144 B: As(33280)+Bs(36864) | tile(512x33 f32)
  __shared__ float scl[512];
  __shared__ float sS[128], sQ[128];     // [row*4 + wave]
  __shared__ float mus[32], rss[32];
  u16* As = (u16*)smemQ;                 // [32][AS2]
  u16* Bs = (u16*)smemQ + 16640;         // [512][BS2]
  float* tile = (float*)smemQ;           // [512][33]
  int m0 = blockIdx.x * 32;
  int b  = m0 >> 10;
  int t0 = m0 & 1023;
  int tid = threadIdx.x;
  int w = tid >> 6, lane = tid & 63;
  int quad = lane >> 4, lr = lane & 15;
  int bb0 = b << 9;
  for (int i = tid; i < 512; i += 256){
    float nv = sqrtf(cn[bb0 + i]);
    scl[i] = 1.f / fmaxf(nv, 1e-12f);
  }
  __syncthreads();
  // stage A-panel resident, scaled: As[row][k]
  {
    int row = tid >> 3, seg = tid & 7;
    const u16* src = &A[(size_t)(m0 + row) * 512 + seg * 64];
    u16* dstl = &As[row * AS2 + seg * 64];
#pragma unroll
    for (int j = 0; j < 8; j++){
      bf16x8 raw = *(const bf16x8*)(src + j*8);
      u16 pk[8];
#pragma unroll
      for (int e = 0; e < 8; e++)
        pk[e] = f2bf(bf2f((u16)raw[e]) * scl[seg*64 + j*8 + e]);
      *(bf16x8*)(dstl + j*8) = *(const bf16x8*)pk;
    }
  }
  // K-loop: stage full 512-col B k-slice per iteration; wave w covers cols w*128..+128
  f32x4 acc[2][8] = {};
  for (int kt = 0; kt < 512; kt += 32){
    __syncthreads();                 // Bs readers done (and As staged, first iter)
#pragma unroll
    for (int half = 0; half < 2; half++){
      int n = tid + half*256;
      const u16* src = &Bt[(size_t)n * 512 + kt];
      u16* dstl = &Bs[n * BS2];
#pragma unroll
      for (int j = 0; j < 4; j++)
        *(bf16x8*)(dstl + j*8) = *(const bf16x8*)(src + j*8);
    }
    __syncthreads();
    bf16x8 af0 = *(const bf16x8*)&As[lr * AS2 + kt + quad*8];
    bf16x8 af1 = *(const bf16x8*)&As[(16 + lr) * AS2 + kt + quad*8];
#pragma unroll
    for (int ni = 0; ni < 8; ni++){
      bf16x8 bfr = *(const bf16x8*)&Bs[(w*128 + ni*16 + lr)*BS2 + quad*8];
      acc[0][ni] = __builtin_amdgcn_mfma_f32_16x16x32_bf16(af0, bfr, acc[0][ni], 0, 0, 0);
      acc[1][ni] = __builtin_amdgcn_mfma_f32_16x16x32_bf16(af1, bfr, acc[1][ni], 0, 0, 0);
    }
  }
  // epilogue A: y = acc + x + b2 (kept in acc); per-row partial stats
  float b2v[8];
#pragma unroll
  for (int ni = 0; ni < 8; ni++) b2v[ni] = b2[w*128 + ni*16 + lr];
#pragma unroll
  for (int mi = 0; mi < 2; mi++)
#pragma unroll
    for (int r = 0; r < 4; r++){
      int row = mi*16 + quad*4 + r;
      float rs = 0.f, rq = 0.f;
#pragma unroll
      for (int ni = 0; ni < 8; ni++){
        int col = w*128 + ni*16 + lr;
        float yv = acc[mi][ni][r] + xres[(size_t)(m0 + row) * 512 + col] + b2v[ni];
        acc[mi][ni][r] = yv;
        rs += yv; rq += yv * yv;
      }
#pragma unroll
      for (int mo = 1; mo < 16; mo <<= 1){
        rs += __shfl_xor(rs, mo, 64);
        rq += __shfl_xor(rq, mo, 64);
      }
      if (lr == 0){ sS[row*4 + w] = rs; sQ[row*4 + w] = rq; }
    }
  __syncthreads();
  if (tid < 32){
    float s = sS[tid*4] + sS[tid*4+1] + sS[tid*4+2] + sS[tid*4+3];
    float q = sQ[tid*4] + sQ[tid*4+1] + sQ[tid*4+2] + sQ[tid*4+3];
    float m = s * (1.f/512.f);
    float var = q * (1.f/512.f) - m * m;
    mus[tid] = m;
    rss[tid] = 1.f / sqrtf(var + 1e-5f);
  }
  __syncthreads();                     // stats ready; As/Bs dead -> tile overlays
  // epilogue B: LN apply + transpose into tile[col][t_local]
  float gv[8], bv[8];
#pragma unroll
  for (int ni = 0; ni < 8; ni++){
    gv[ni] = g[w*128 + ni*16 + lr];
    bv[ni] = bb[w*128 + ni*16 + lr];
  }
#pragma unroll
  for (int mi = 0; mi < 2; mi++)
#pragma unroll
    for (int r = 0; r < 4; r++){
      int row = mi*16 + quad*4 + r;
      float mu_ = mus[row], rs_ = rss[row];
#pragma unroll
      for (int ni = 0; ni < 8; ni++){
        int col = w*128 + ni*16 + lr;
        tile[col*33 + row] = (acc[mi][ni][r] - mu_) * rs_ * gv[ni] + bv[ni];
      }
    }
  __syncthreads();
  // epilogue C: coalesced out writes — 2 cols per thread, 32 t each (128 B runs)
  {
    size_t obase = (size_t)b * 512 * 1024 + t0;
#pragma unroll
    for (int cc = 0; cc < 2; cc++){
      int col = tid*2 + cc;
      const float* srcp = &tile[col*33];
      float* dst = &out[obase + (size_t)col * 1024];
#pragma unroll
      for (int j = 0; j < 8; j++){
        f32x4 v;
#pragma unroll
        for (int e = 0; e < 4; e++) v[e] = srcp[j*4 + e];
        *(f32x4*)(dst + j*4) = v;
      }
    }
  }
}

extern "C" void kernel_launch(void* const* d_in, const int* in_sizes, int n_in,
                              void* d_out, int out_size, void* d_ws, size_t ws_size,
                              hipStream_t stream) {
  (void)in_sizes; (void)n_in; (void)out_size; (void)ws_size;
  const float* x     = (const float*)d_in[0];
  const float* W     = (const float*)d_in[1];
  const float* a_src = (const float*)d_in[2];
  const float* a_dst = (const float*)d_in[3];
  const float* W2    = (const float*)d_in[4];
  const float* b2    = (const float*)d_in[5];
  const float* ln_g  = (const float*)d_in[6];
  const float* ln_b  = (const float*)d_in[7];
  char* ws = (char*)d_ws;
  int*   sel   = (int*)  (ws + 256);
  float* mags  = (float*)(ws + 33024);
  u16*   WcatT = (u16*)  (ws + 65792);
  u16*   W2T   = (u16*)  (ws + 590080);
  float* es    = (float*)(ws + 1124608);
  float* ed    = (float*)(ws + 1386752);
  float* cn    = (float*)(ws + 1648896);   // 16 KB
  u16*   WhT   = (u16*)  (ws + 2097152);   // 8 MB; dead after k_attn
  u16*   t2b   = (u16*)  (ws + 18874368);  // 8 MB
  float* out   = (float*)d_out;

  k_convert_w<<<2048, 256, 0, stream>>>(W, W2, WcatT, W2T);
  hipMemsetAsync(cn, 0, 16384, stream);    // cn only
  k_gemm_wh  <<<dim3(64, 8), 256, 0, stream>>>(x, WcatT, a_src, a_dst, WhT, es, ed, mags);
  k_select   <<<dim3(NB, 16), 256, 0, stream>>>(mags, sel);
  k_attn     <<<dim3(64, 16), 256, 0, stream>>>(WhT, es, ed, sel, t2b, cn);
  k_gemm2out <<<256, 256, 0, stream>>>(t2b, W2T, x, b2, cn, ln_g, ln_b, out);
}

// Round 12
// 158.231 us; speedup vs baseline: 1.1497x; 1.1497x over previous
//
#include <hip/hip_runtime.h>
#include <hip/hip_bf16.h>

typedef unsigned short u16;
typedef short bf16x8 __attribute__((ext_vector_type(8)));
typedef float f32x4 __attribute__((ext_vector_type(4)));
typedef int   i32x4 __attribute__((ext_vector_type(4)));

#define NB 8
#define NT 1024
#define ND 512
#define KSEL 307
#define PSTR 152   // attn P LDS row stride (elems)
#define TSTR 136   // gemm_wh transpose LDS row stride (elems)

__device__ __forceinline__ float bf2f(u16 u){
  union { unsigned int i; float f; } c; c.i = ((unsigned int)u) << 16; return c.f;
}
__device__ __forceinline__ u16 f2bf(float f){
  __hip_bfloat16 h = __float2bfloat16(f);
  u16 u; __builtin_memcpy(&u, &h, 2); return u;
}

// ---------- exact top-k selection by ranking; 4 threads per t, 64 t per block
//            + fused cn zeroing (block (b,by) owns cn[b*512 + by*32 ..+32])
__global__ void k_select(const float* __restrict__ mags, int* __restrict__ sel,
                         float* __restrict__ cn){
  __shared__ float sm[NT];
  int b = blockIdx.x;
  int tid = threadIdx.x;
  if (tid < 32) cn[b * ND + blockIdx.y * 32 + tid] = 0.f;
  for (int i = tid; i < NT; i += 256) sm[i] = mags[b * NT + i];
  __syncthreads();
  int tl = tid >> 2, tq = tid & 3;
  int t = blockIdx.y * 64 + tl;
  float m = sm[t];
  int cnt = 0;
  int s0 = tq * 256;
  for (int s = s0; s < s0 + 256; s++){
    float v = sm[s];
    cnt += (v > m) || (v == m && s < t);
  }
  cnt += __shfl_xor(cnt, 1, 64);
  cnt += __shfl_xor(cnt, 2, 64);
  if (tq == 0) sel[b * NT + t] = (cnt < KSEL) ? 1 : 0;
}

// ---------- MFMA bf16 GEMM: Wh = bf16(x) @ Wcat ; tile 128(t) x 64(f = one head)
//   B staged directly from W (f32, W[h][k][f]) with inline bf16 conversion.
//   epilogue fuses: row mags (by==0), es/ed edge dots, transposed bf16 WhT write
__launch_bounds__(256, 3)
__global__ void k_gemm_wh(const float* __restrict__ x, const float* __restrict__ Wf,
                          const float* __restrict__ a_src, const float* __restrict__ a_dst,
                          u16* __restrict__ WhT, float* __restrict__ es, float* __restrict__ ed,
                          float* __restrict__ mags){
  __shared__ u16 smem[8704];         // 17408 B; As(5120)+Bs(2560) alias Tr(64*TSTR)
  u16* As = smem;                    // 128 x 40
  u16* Bs = smem + 5120;             // 64 x 40
  int m0 = blockIdx.x * 128;         // t-block
  int h  = blockIdx.y;               // head (n0 = h*64)
  int tid = threadIdx.x;
  int wv = tid >> 6, lane = tid & 63;
  int quad = lane >> 4, lr = lane & 15;
  f32x4 acc[2][4] = {};
  float sq[2] = {0.f, 0.f};
  for (int kt = 0; kt < 512; kt += 32){
    __syncthreads();
#pragma unroll
    for (int i = 0; i < 2; i++){
      int e = tid * 8 + i * 2048;
      int r = e >> 5, c = e & 31;
      const float* xa = &x[(m0 + r) * 512 + kt + c];
      f32x4 u0 = *(const f32x4*)xa;
      f32x4 u1 = *(const f32x4*)(xa + 4);
      u16 pk[8];
#pragma unroll
      for (int q = 0; q < 4; q++){
        sq[i] += u0[q]*u0[q] + u1[q]*u1[q];
        pk[q] = f2bf(u0[q]); pk[4+q] = f2bf(u1[q]);
      }
      *(bf16x8*)&As[r*40 + c] = *(const bf16x8*)pk;
    }
    {
      int e = tid * 8;               // 0..2047 exactly covers 64(f) x 32(k)
      int r = e >> 5, c = e & 31;    // r = f, c = k-offset (multiple of 8)
      const float* wsrc = &Wf[((size_t)h << 15) + (size_t)(kt + c) * 64 + r];
      u16 pk[8];
#pragma unroll
      for (int q = 0; q < 8; q++) pk[q] = f2bf(wsrc[q * 64]);
      *(bf16x8*)&Bs[r*40 + c] = *(const bf16x8*)pk;
    }
    __syncthreads();
    bf16x8 af[2], bfr[4];
#pragma unroll
    for (int i = 0; i < 2; i++) af[i] = *(const bf16x8*)&As[(wv*32 + i*16 + lr)*40 + quad*8];
#pragma unroll
    for (int i = 0; i < 4; i++) bfr[i] = *(const bf16x8*)&Bs[(i*16 + lr)*40 + quad*8];
#pragma unroll
    for (int mi = 0; mi < 2; mi++)
#pragma unroll
      for (int ni = 0; ni < 4; ni++)
        acc[mi][ni] = __builtin_amdgcn_mfma_f32_16x16x32_bf16(af[mi], bfr[ni], acc[mi][ni], 0, 0, 0);
  }
  // ---- epilogue 0: row L2 norms (4 lanes per row)
  if (blockIdx.y == 0){
#pragma unroll
    for (int i = 0; i < 2; i++){
      float s = sq[i];
      s += __shfl_xor(s, 1, 64);
      s += __shfl_xor(s, 2, 64);
      if ((tid & 3) == 0) mags[m0 + i*64 + (tid >> 2)] = sqrtf(s);
    }
  }
  // ---- epilogue 1: edge dot products (wave owns rows wv*32..+32, full head width)
  float asv[4], adv[4];
#pragma unroll
  for (int ni = 0; ni < 4; ni++){
    asv[ni] = a_src[h*64 + ni*16 + lr];
    adv[ni] = a_dst[h*64 + ni*16 + lr];
  }
#pragma unroll
  for (int mi = 0; mi < 2; mi++)
#pragma unroll
    for (int r = 0; r < 4; r++){
      float pes = 0.f, ped = 0.f;
#pragma unroll
      for (int ni = 0; ni < 4; ni++){
        pes += acc[mi][ni][r] * asv[ni];
        ped += acc[mi][ni][r] * adv[ni];
      }
#pragma unroll
      for (int mofs = 1; mofs < 16; mofs <<= 1){
        pes += __shfl_xor(pes, mofs, 64);
        ped += __shfl_xor(ped, mofs, 64);
      }
      if (lr == 0){
        int rowg = m0 + wv*32 + mi*16 + quad*4 + r;
        int bb_ = rowg >> 10, tt = rowg & 1023;
        es[(bb_ * 8 + h) * NT + tt] = pes;
        ed[(bb_ * 8 + h) * NT + tt] = ped;
      }
    }
  // ---- epilogue 2: bf16 transpose via LDS -> WhT[(b*512 + h*64 + f)][t]
  __syncthreads();
  u16* Tr = smem;   // [f][t], stride TSTR
#pragma unroll
  for (int mi = 0; mi < 2; mi++)
#pragma unroll
    for (int ni = 0; ni < 4; ni++){
      int fl = ni*16 + lr;
      int tl = wv*32 + mi*16 + quad*4;
#pragma unroll
      for (int r = 0; r < 4; r++) Tr[fl*TSTR + tl + r] = f2bf(acc[mi][ni][r]);
    }
  __syncthreads();
  int f = tid >> 2, seg = tid & 3;
  int b_ = m0 >> 10;
  u16* dst = &WhT[(b_ * 512 + h * 64 + f) * NT + (m0 & 1023) + seg*32];
  const u16* srcp = &Tr[f*TSTR + seg*32];
#pragma unroll
  for (int k8 = 0; k8 < 4; k8++)
    *(bf16x8*)(dst + k8*8) = *(const bf16x8*)(srcp + k8*8);
}

// ---------- banded masked attention via MFMA + elu + signed-sqrt -> t2b (bf16)
//            + fused column sum-of-squares (atomicAdd into cn)
__launch_bounds__(256)
__global__ void k_attn(const u16* __restrict__ WhT, const float* __restrict__ es,
                       const float* __restrict__ ed, const int* __restrict__ sel,
                       u16* __restrict__ t2b, float* __restrict__ cn){
  __shared__ u16 P[64 * PSTR];
  __shared__ float edw[144];
  __shared__ int   selw[144];
  __shared__ float esw[64];
  __shared__ float swv[64];
  int bh = blockIdx.x;               // b*8+h
  int b = bh >> 3;
  int t0 = blockIdx.y * 64;
  int tid = threadIdx.x;
  int wv = tid >> 6, lane = tid & 63;
  int quad = lane >> 4, lr = lane & 15;
  int s_base = t0 - 40;
  for (int i = tid; i < 144; i += 256){
    int s = s_base + i;
    bool ok = (s >= 0 && s < NT);
    edw[i]  = ok ? ed[bh * NT + s] : 0.f;
    selw[i] = ok ? sel[b * NT + s] : 0;
  }
  if (tid < 64) esw[tid] = es[bh * NT + t0 + tid];
  {
    i32x4 z = {};
    for (int i = lane; i < 304; i += 64){
      int r16 = i / 19, c16 = i - r16 * 19;
      *(i32x4*)&P[(16*wv + r16) * PSTR + c16 * 8] = z;
    }
  }
  __syncthreads();
  {
    int tl = 16*wv + (lane >> 2);
    int q = lane & 3;
    float e_t = esw[tl];
    int sel_t = selw[tl + 40];
    float part = 0.f;
    for (int j = q; j <= 80; j += 4){
      int sw = tl + j;
      int s = s_base + sw;
      float w = 0.f;
      if (s >= 0 && s < NT && (sel_t | selw[sw])){
        float v = e_t + edw[sw];
        v = v > 0.f ? v : 0.2f * v;
        v = fminf(v, 60.f);
        w = bf2f(f2bf(__expf(v)));
      }
      part += w;
      if (w != 0.f) P[tl * PSTR + sw] = f2bf(w);
    }
    part += __shfl_xor(part, 1, 64);
    part += __shfl_xor(part, 2, 64);
    if (q == 0) swv[tl] = part;
  }
  f32x4 acc[4] = {};
  const u16* vbase = WhT + (bh * 64) * NT;
#pragma unroll
  for (int ks = 0; ks < 96; ks += 32){
    bf16x8 afr = *(const bf16x8*)&P[(16*wv + lr) * PSTR + 16*wv + ks + quad*8];
    int tb = s_base + 16*wv + ks + quad*8;
    bool ok = (tb >= 0) && (tb < NT);
    bf16x8 zf = {};
#pragma unroll
    for (int jn = 0; jn < 4; jn++){
      bf16x8 bfr = ok ? *(const bf16x8*)&vbase[(16*jn + lr) * NT + tb] : zf;
      acc[jn] = __builtin_amdgcn_mfma_f32_16x16x32_bf16(afr, bfr, acc[jn], 0, 0, 0);
    }
  }
#pragma unroll
  for (int jn = 0; jn < 4; jn++){
    float ssum = 0.f;
#pragma unroll
    for (int r = 0; r < 4; r++){
      int t_loc = 16*wv + quad*4 + r;
      float sw_ = swv[t_loc];
      float hp = acc[jn][r] / (sw_ > 0.f ? sw_ : 1.f);
      hp = hp > 0.f ? hp : (__expf(hp) - 1.f);
      float o = hp >= 0.f ? sqrtf(hp) : -sqrtf(-hp);
      ssum += o * o;
      t2b[(b * NT + t0 + t_loc) * ND + (bh & 7) * 64 + 16*jn + lr] = f2bf(o);
    }
    ssum += __shfl_xor(ssum, 16, 64);
    ssum += __shfl_xor(ssum, 32, 64);
    if (quad == 0) atomicAdd(&cn[b * ND + (bh & 7) * 64 + 16*jn + lr], ssum);
  }
}

// ---------- GEMM2: Y = (t2b*scl) @ W2 + x + b2 ; tile 128 x 64 ; fused LN partials
//   B staged directly from W2 (f32, W2[k][n]) with inline bf16 conversion.
__launch_bounds__(256, 3)
__global__ void k_gemm2(const u16* __restrict__ A, const float* __restrict__ W2f,
                        const float* __restrict__ xres, const float* __restrict__ b2,
                        const float* __restrict__ cn, float* __restrict__ Y,
                        float* __restrict__ rsum, float* __restrict__ rqsum){
  __shared__ u16 As[128 * 40];
  __shared__ u16 Bs[64 * 40];
  __shared__ float scl[512];
  int m0 = blockIdx.x * 128, n0 = blockIdx.y * 64;
  int tid = threadIdx.x;
  int wv = tid >> 6, lane = tid & 63;
  int quad = lane >> 4, lr = lane & 15;
  int bb0 = (m0 >> 10) << 9;          // b*512
  for (int i = tid; i < 512; i += 256){
    float nv = sqrtf(cn[bb0 + i]);
    scl[i] = 1.f / fmaxf(nv, 1e-12f);
  }
  f32x4 acc[2][4] = {};
  for (int kt = 0; kt < 512; kt += 32){
    __syncthreads();
#pragma unroll
    for (int i = 0; i < 2; i++){
      int e = tid * 8 + i * 2048;
      int r = e >> 5, c = e & 31;
      bf16x8 raw = *(const bf16x8*)&A[(m0 + r) * 512 + kt + c];
      u16 pk[8];
#pragma unroll
      for (int q = 0; q < 8; q++)
        pk[q] = f2bf(bf2f((u16)raw[q]) * scl[kt + c + q]);
      *(bf16x8*)&As[r*40 + c] = *(const bf16x8*)pk;
    }
    {
      int e = tid * 8;               // r = n-offset 0..63, c = k-offset
      int r = e >> 5, c = e & 31;
      const float* wsrc = &W2f[(size_t)(kt + c) * 512 + n0 + r];
      u16 pk[8];
#pragma unroll
      for (int q = 0; q < 8; q++) pk[q] = f2bf(wsrc[q * 512]);
      *(bf16x8*)&Bs[r*40 + c] = *(const bf16x8*)pk;
    }
    __syncthreads();
    bf16x8 af[2], bfr[4];
#pragma unroll
    for (int i = 0; i < 2; i++) af[i] = *(const bf16x8*)&As[(wv*32 + i*16 + lr)*40 + quad*8];
#pragma unroll
    for (int i = 0; i < 4; i++) bfr[i] = *(const bf16x8*)&Bs[(i*16 + lr)*40 + quad*8];
#pragma unroll
    for (int mi = 0; mi < 2; mi++)
#pragma unroll
      for (int ni = 0; ni < 4; ni++)
        acc[mi][ni] = __builtin_amdgcn_mfma_f32_16x16x32_bf16(af[mi], bfr[ni], acc[mi][ni], 0, 0, 0);
  }
  float b2v[4];
#pragma unroll
  for (int ni = 0; ni < 4; ni++) b2v[ni] = b2[n0 + ni*16 + lr];
#pragma unroll
  for (int mi = 0; mi < 2; mi++){
    int rgb = m0 + wv*32 + mi*16 + quad*4;
#pragma unroll
    for (int r = 0; r < 4; r++){
      int row = rgb + r;
      float rs = 0.f, rq = 0.f;
#pragma unroll
      for (int ni = 0; ni < 4; ni++){
        int cg = n0 + ni*16 + lr;
        int idx = row * 512 + cg;
        float yv = acc[mi][ni][r] + xres[idx] + b2v[ni];
        Y[idx] = yv;
        rs += yv; rq += yv * yv;
      }
#pragma unroll
      for (int m2 = 1; m2 < 16; m2 <<= 1){
        rs += __shfl_xor(rs, m2, 64);
        rq += __shfl_xor(rq, m2, 64);
      }
      if (lr == 0){
        atomicAdd(&rsum[row], rs);
        atomicAdd(&rqsum[row], rq);
      }
    }
  }
}

// ---------- LN apply (stats precomputed) + transpose; block = 64 t x 128 d
__global__ void k_outln(const float* __restrict__ Y, const float* __restrict__ rsum,
                        const float* __restrict__ rqsum, const float* __restrict__ g,
                        const float* __restrict__ bb, float* __restrict__ out){
  __shared__ float mus[64], rss[64];
  __shared__ float tile[64 * 65];
  int t0 = blockIdx.x * 64, b = blockIdx.y;
  int cbase = blockIdx.z * 128;
  int tid = threadIdx.x;
  if (tid < 64){
    int row = b * NT + t0 + tid;
    float m = rsum[row] * (1.f/512.f);
    float var = rqsum[row] * (1.f/512.f) - m * m;
    mus[tid] = m;
    rss[tid] = 1.f / sqrtf(var + 1e-5f);
  }
  __syncthreads();
  int j = tid & 63, i0 = tid >> 6;
  for (int c0 = cbase; c0 < cbase + 128; c0 += 64){
#pragma unroll
    for (int k = 0; k < 16; k++){
      int i = i0 + k * 4;
      float v = (Y[(b * NT + t0 + i) * ND + c0 + j] - mus[i]) * rss[i] * g[c0 + j] + bb[c0 + j];
      tile[i * 65 + j] = v;
    }
    __syncthreads();
#pragma unroll
    for (int k = 0; k < 16; k++){
      int jj = i0 + k * 4;   // d-local
      out[(b * ND + c0 + jj) * NT + t0 + j] = tile[j * 65 + jj];
    }
    __syncthreads();
  }
}

extern "C" void kernel_launch(void* const* d_in, const int* in_sizes, int n_in,
                              void* d_out, int out_size, void* d_ws, size_t ws_size,
                              hipStream_t stream) {
  (void)in_sizes; (void)n_in; (void)out_size; (void)ws_size;
  const float* x     = (const float*)d_in[0];
  const float* W     = (const float*)d_in[1];
  const float* a_src = (const float*)d_in[2];
  const float* a_dst = (const float*)d_in[3];
  const float* W2    = (const float*)d_in[4];
  const float* b2    = (const float*)d_in[5];
  const float* ln_g  = (const float*)d_in[6];
  const float* ln_b  = (const float*)d_in[7];
  char* ws = (char*)d_ws;
  int*   sel   = (int*)  (ws + 256);
  float* mags  = (float*)(ws + 33024);
  float* es    = (float*)(ws + 1124608);
  float* ed    = (float*)(ws + 1386752);
  float* cn    = (float*)(ws + 1648896);   // 16 KB (zeroed in k_select)
  float* rsum  = (float*)(ws + 1665280);   // 32 KB
  float* rqsum = (float*)(ws + 1698048);   // 32 KB
  u16*   WhT   = (u16*)  (ws + 2097152);   // 8 MB; dead after k_attn
  u16*   t2b   = (u16*)  (ws + 18874368);  // 8 MB
  float* Y     = (float*)(ws + 2097152);   // 16 MB; overlays WhT after dead
  float* out   = (float*)d_out;

  hipMemsetAsync(rsum, 0, 65536, stream);  // rsum + rqsum
  k_gemm_wh  <<<dim3(64, 8), 256, 0, stream>>>(x, W, a_src, a_dst, WhT, es, ed, mags);
  k_select   <<<dim3(NB, 16), 256, 0, stream>>>(mags, sel, cn);
  k_attn     <<<dim3(64, 16), 256, 0, stream>>>(WhT, es, ed, sel, t2b, cn);
  k_gemm2    <<<dim3(64, 8), 256, 0, stream>>>(t2b, W2, x, b2, cn, Y, rsum, rqsum);
  k_outln    <<<dim3(16, NB, 4), 256, 0, stream>>>(Y, rsum, rqsum, ln_g, ln_b, out);
}